// Round 1
// baseline (84.409 us; speedup 1.0000x reference)
//
#include <hip/hip_runtime.h>

// Problem constants (match reference)
#define S_AR 3072
#define NH 16
#define NB 4
#define ND 128
#define NTOT (S_AR * NH * NB * ND)          // 25,165,824 elems per tensor
#define N4   (NTOT / 4)                     // float4 count per tensor

__device__ __forceinline__ float inv_max_int8() { return 1.0f / 127.5f; }

// Main streaming pass: out = cached_q * (scale * (1/127.5)) for both K and V.
// Row `idx` gets (temporarily wrong) values here; the fixup kernel overwrites it.
__global__ void __launch_bounds__(256) dequant_stream(
    const float4* __restrict__ ck, const float4* __restrict__ cv,
    const float*  __restrict__ ksc, const float* __restrict__ vsc,
    float4* __restrict__ ok, float4* __restrict__ ov)
{
    const float inv = inv_max_int8();
    int stride = gridDim.x * blockDim.x;
    for (int i = blockIdx.x * blockDim.x + threadIdx.x; i < N4; i += stride) {
        int row = i >> 5;                    // 128 elems = 32 float4 per (s,h,b) row
        float ks = ksc[row] * inv;
        float vs = vsc[row] * inv;
        float4 k = ck[i];
        float4 v = cv[i];
        k.x *= ks; k.y *= ks; k.z *= ks; k.w *= ks;
        v.x *= vs; v.y *= vs; v.z *= vs; v.w *= vs;
        ok[i] = k;
        ov[i] = v;
    }
}

// Fixup: quantize the new K/V step per (b,h) (abs-max over D), dequantize,
// and write into output row s = *idxp. 128 blocks (b,h,kv) x 64 threads (1 wave).
__global__ void __launch_bounds__(64) write_new_row(
    const float* __restrict__ key, const float* __restrict__ value,
    const int* __restrict__ idxp, float* __restrict__ out_k, float* __restrict__ out_v)
{
    int g  = blockIdx.x;          // 0..127
    int kv = g & 1;               // 0 = key, 1 = value
    int bh = g >> 1;              // 0..63
    int b  = bh / NH;
    int h  = bh % NH;

    // new step, logical layout (B,1,H,D): offset (b*H + h)*D
    const float* src = (kv ? value : key) + (b * NH + h) * ND;
    int lane = threadIdx.x;       // 0..63
    float x0 = src[lane];
    float x1 = src[lane + 64];

    float m = fmaxf(fabsf(x0), fabsf(x1));
    #pragma unroll
    for (int off = 32; off; off >>= 1)
        m = fmaxf(m, __shfl_xor(m, off));

    float qs = 127.5f / m;               // quantize scale (matches ref order)
    float ds = m * inv_max_int8();       // dequantize scale

    int idx = *idxp;
    // stored layout (S,H,B,D): offset ((s*H + h)*B + b)*D
    float* dst = (kv ? out_v : out_k) + (((size_t)idx * NH + h) * NB + b) * ND;
    dst[lane]      = rintf(x0 * qs) * ds;
    dst[lane + 64] = rintf(x1 * qs) * ds;
}

extern "C" void kernel_launch(void* const* d_in, const int* in_sizes, int n_in,
                              void* d_out, int out_size, void* d_ws, size_t ws_size,
                              hipStream_t stream) {
    const float* key   = (const float*)d_in[0];
    const float* value = (const float*)d_in[1];
    const float* ck    = (const float*)d_in[2];
    const float* cv    = (const float*)d_in[3];
    const float* ksc   = (const float*)d_in[4];
    const float* vsc   = (const float*)d_in[5];
    const int*   idxp  = (const int*)d_in[6];

    float* out_k = (float*)d_out;
    float* out_v = (float*)d_out + NTOT;

    dim3 block(256);
    dim3 grid(2048);              // 256 CU x 8 blocks, grid-stride covers N4
    dequant_stream<<<grid, block, 0, stream>>>(
        (const float4*)ck, (const float4*)cv, ksc, vsc,
        (float4*)out_k, (float4*)out_v);

    write_new_row<<<dim3(128), dim3(64), 0, stream>>>(key, value, idxp, out_k, out_v);
}

// Round 3
// 76.451 us; speedup vs baseline: 1.1041x; 1.1041x over previous
//
#include <hip/hip_runtime.h>

// Problem constants (match reference)
#define S_AR 3072
#define NH 16
#define NB 4
#define ND 128
#define NTOT (S_AR * NH * NB * ND)   // 25,165,824 elems per tensor
#define N4   (NTOT / 4)              // 6,291,456 float4 per tensor
#define TPB 256
#define BLOCKS 2048
#define STRIDE (BLOCKS * TPB)        // 524,288 threads
#define ITERS (N4 / STRIDE)          // exactly 12, no remainder

// Native clang vector type — required by __builtin_nontemporal_{load,store}
typedef float vf4 __attribute__((ext_vector_type(4)));

__device__ __forceinline__ float max4abs(vf4 a) {
    return fmaxf(fmaxf(fabsf(a.x), fabsf(a.y)), fmaxf(fabsf(a.z), fabsf(a.w)));
}

// Fused: streaming dequant of both caches + in-place quantize/dequant of the
// new K/V step at row s==idx. One (s,h,b) row = 128 floats = 32 float4 = one
// aligned 32-lane group, so the abs-max over D reduces via __shfl_xor(<=16).
__global__ void __launch_bounds__(TPB) kv_dequant_fused(
    const vf4* __restrict__ key4, const vf4* __restrict__ val4,
    const vf4* __restrict__ ck,   const vf4* __restrict__ cv,
    const float* __restrict__ ksc, const float* __restrict__ vsc,
    const int* __restrict__ idxp,
    vf4* __restrict__ ok, vf4* __restrict__ ov)
{
    const float inv = 1.0f / 127.5f;
    const int idx = *idxp;                      // uniform scalar load
    const int tid = blockIdx.x * TPB + threadIdx.x;

    #pragma unroll
    for (int it = 0; it < ITERS; ++it) {
        const int i   = tid + it * STRIDE;
        const int row = i >> 5;                 // (s,h,b) flat row
        vf4 k, v;
        if ((row >> 6) != idx) {                // s != idx : plain dequant
            const float ks = ksc[row] * inv;
            const float vs = vsc[row] * inv;
            k = __builtin_nontemporal_load(&ck[i]);
            v = __builtin_nontemporal_load(&cv[i]);
            k *= ks;
            v *= vs;
        } else {                                // s == idx : quantize new step
            const int h = (row >> 2) & 15;
            const int b = row & 3;
            const int off = (b * NH + h) * (ND / 4) + (i & 31);
            const vf4 kn = key4[off];
            const vf4 vn = val4[off];
            float mk = max4abs(kn);
            float mv = max4abs(vn);
            #pragma unroll
            for (int o = 16; o; o >>= 1) {      // stays within the 32-lane group
                mk = fmaxf(mk, __shfl_xor(mk, o));
                mv = fmaxf(mv, __shfl_xor(mv, o));
            }
            const float qk = 127.5f / mk, dk = mk * inv;
            const float qv = 127.5f / mv, dv = mv * inv;
            k.x = rintf(kn.x * qk) * dk; k.y = rintf(kn.y * qk) * dk;
            k.z = rintf(kn.z * qk) * dk; k.w = rintf(kn.w * qk) * dk;
            v.x = rintf(vn.x * qv) * dv; v.y = rintf(vn.y * qv) * dv;
            v.z = rintf(vn.z * qv) * dv; v.w = rintf(vn.w * qv) * dv;
        }
        __builtin_nontemporal_store(k, &ok[i]);
        __builtin_nontemporal_store(v, &ov[i]);
    }
}

extern "C" void kernel_launch(void* const* d_in, const int* in_sizes, int n_in,
                              void* d_out, int out_size, void* d_ws, size_t ws_size,
                              hipStream_t stream) {
    const float* key   = (const float*)d_in[0];
    const float* value = (const float*)d_in[1];
    const float* ck    = (const float*)d_in[2];
    const float* cv    = (const float*)d_in[3];
    const float* ksc   = (const float*)d_in[4];
    const float* vsc   = (const float*)d_in[5];
    const int*   idxp  = (const int*)d_in[6];

    float* out_k = (float*)d_out;
    float* out_v = (float*)d_out + NTOT;

    kv_dequant_fused<<<dim3(BLOCKS), dim3(TPB), 0, stream>>>(
        (const vf4*)key, (const vf4*)value,
        (const vf4*)ck, (const vf4*)cv,
        ksc, vsc, idxp,
        (vf4*)out_k, (vf4*)out_v);
}

// Round 4
// 74.148 us; speedup vs baseline: 1.1384x; 1.0311x over previous
//
#include <hip/hip_runtime.h>

// Problem constants (match reference)
#define S_AR 3072
#define NH 16
#define NB 4
#define ND 128
#define NTOT (S_AR * NH * NB * ND)   // 25,165,824 elems per tensor
#define N4   (NTOT / 4)              // 6,291,456 float4 per tensor
#define TPB 256
#define HALF_BLOCKS 2048             // blocks per tensor
#define STRIDE (HALF_BLOCKS * TPB)   // 524,288 threads per tensor
#define ITERS (N4 / STRIDE)          // exactly 12, no remainder

// Native clang vector type — required by __builtin_nontemporal_{load,store}
typedef float vf4 __attribute__((ext_vector_type(4)));

__device__ __forceinline__ float max4abs(vf4 a) {
    return fmaxf(fmaxf(fabsf(a.x), fabsf(a.y)), fmaxf(fabsf(a.z), fabsf(a.w)));
}

// K/V-split streaming dequant. Blocks [0,HALF_BLOCKS) stream the K cache,
// [HALF_BLOCKS,2*HALF_BLOCKS) the V cache: 1 load + 1 store stream per thread.
// Hot path is branchless; the 64 special rows (s == idx) take a cold block
// that re-quantizes the new decode step (32-lane-group __shfl_xor abs-max).
__global__ void __launch_bounds__(TPB) kv_dequant_split(
    const vf4* __restrict__ key4, const vf4* __restrict__ val4,
    const vf4* __restrict__ ck,   const vf4* __restrict__ cv,
    const float* __restrict__ ksc, const float* __restrict__ vsc,
    const int* __restrict__ idxp,
    vf4* __restrict__ ok, vf4* __restrict__ ov)
{
    const float inv = 1.0f / 127.5f;
    const int idx = *idxp;                        // uniform scalar load
    const int half = blockIdx.x >> 11;            // 0 = K, 1 = V
    const int tid  = (blockIdx.x & (HALF_BLOCKS - 1)) * TPB + threadIdx.x;

    const vf4*   src  = half ? cv   : ck;
    const float* sc   = half ? vsc  : ksc;
    const vf4*   new4 = half ? val4 : key4;
    vf4*         dst  = half ? ov   : ok;

    #pragma unroll
    for (int it = 0; it < ITERS; ++it) {
        const int i   = tid + it * STRIDE;
        const int row = i >> 5;                   // (s,h,b) flat row
        vf4 x = __builtin_nontemporal_load(&src[i]);
        x *= sc[row] * inv;
        if (__builtin_expect((row >> 6) == idx, 0)) {   // s == idx : new step
            const int h = (row >> 2) & 15;
            const int b = row & 3;
            const vf4 n = new4[(b * NH + h) * (ND / 4) + (i & 31)];
            float m = max4abs(n);
            #pragma unroll
            for (int o = 16; o; o >>= 1)          // stays within 32-lane group
                m = fmaxf(m, __shfl_xor(m, o));
            const float q = 127.5f / m, d = m * inv;
            x.x = rintf(n.x * q) * d; x.y = rintf(n.y * q) * d;
            x.z = rintf(n.z * q) * d; x.w = rintf(n.w * q) * d;
        }
        __builtin_nontemporal_store(x, &dst[i]);
    }
}

extern "C" void kernel_launch(void* const* d_in, const int* in_sizes, int n_in,
                              void* d_out, int out_size, void* d_ws, size_t ws_size,
                              hipStream_t stream) {
    const float* key   = (const float*)d_in[0];
    const float* value = (const float*)d_in[1];
    const float* ck    = (const float*)d_in[2];
    const float* cv    = (const float*)d_in[3];
    const float* ksc   = (const float*)d_in[4];
    const float* vsc   = (const float*)d_in[5];
    const int*   idxp  = (const int*)d_in[6];

    float* out_k = (float*)d_out;
    float* out_v = (float*)d_out + NTOT;

    kv_dequant_split<<<dim3(2 * HALF_BLOCKS), dim3(TPB), 0, stream>>>(
        (const vf4*)key, (const vf4*)value,
        (const vf4*)ck, (const vf4*)cv,
        ksc, vsc, idxp,
        (vf4*)out_k, (vf4*)out_v);
}